// Round 2
// baseline (196.202 us; speedup 1.0000x reference)
//
#include <hip/hip_runtime.h>
#include <hip/hip_bf16.h>

// Problem: B=2048, D=512, all fp32.
// q = query@Wq.T+bq ; k,v likewise. attn[b,i,j]=q_i*k_j (rank-1!),
// softmax over j, out[b,i] = sum_j softmax_j(q_i*k_j)*v_j.
// => out[b,i] = f_b(q[b,i]) computed with a D-length exp reduction.

#define B_SZ 2048
#define D_SZ 512

// Guaranteed-raw hardware exp2. Library exp2f() without fast-math emits a
// denormal-safe expansion (~4 extra VALU/exp) — that was ~+30% on the attn
// kernel's VALU pipe in round 1.
__device__ __forceinline__ float exp2_raw(float x) {
#if defined(__has_builtin) && __has_builtin(__builtin_amdgcn_exp2f)
    return __builtin_amdgcn_exp2f(x);
#else
    float r;
    asm("v_exp_f32 %0, %1" : "=v"(r) : "v"(x));
    return r;
#endif
}

// ---------------------------------------------------------------------------
// Kernel 1: Y = X @ W^T + bias  for (query,Wq,bq), (key,Wk,bk), (value,Wv,bv)
// selected by blockIdx.z. fp32 (no fp32 MFMA on CDNA4 -> vector ALU).
// Tile: BM=BN=64, BK=32; 256 threads; 4x4 acc/thread; register-prefetch
// software pipeline (global loads for tile kk+1 issue before compute of kk).
// ---------------------------------------------------------------------------
__global__ __launch_bounds__(256) void qkv_gemm(
    const float* __restrict__ Xq, const float* __restrict__ Xk, const float* __restrict__ Xv,
    const float* __restrict__ Wq, const float* __restrict__ bq,
    const float* __restrict__ Wk, const float* __restrict__ bk,
    const float* __restrict__ Wv, const float* __restrict__ bv,
    float* __restrict__ qkv_out)
{
    const int which = blockIdx.z;
    const float* __restrict__ X    = (which == 0) ? Xq : (which == 1) ? Xk : Xv;
    const float* __restrict__ W    = (which == 0) ? Wq : (which == 1) ? Wk : Wv;
    const float* __restrict__ bias = (which == 0) ? bq : (which == 1) ? bk : bv;
    float* __restrict__ Y = qkv_out + (size_t)which * B_SZ * D_SZ;

    const int t  = threadIdx.x;
    const int tx = t & 15;        // output col group
    const int ty = t >> 4;        // output row group
    const int m0 = blockIdx.x * 64;
    const int n0 = blockIdx.y * 64;

    // +4 pad keeps float4 alignment (68*4B = 272B, mult of 16); transposed
    // staging writes are 4-way bank-conflicted but cost ~4% of tile cycles.
    __shared__ float Xs[32][68];
    __shared__ float Ws[32][68];

    float acc[4][4] = {{0.f}};

    // staging: 64 rows x 8 float4-cols per operand, 2 rows/thread
    const int r0 = t >> 3;               // 0..31
    const int c0 = (t & 7) * 4;          // 0,4,...,28
    const int r1 = r0 + 32;              // 32..63

    const float* Xp0 = &X[(size_t)(m0 + r0) * D_SZ + c0];
    const float* Xp1 = &X[(size_t)(m0 + r1) * D_SZ + c0];
    const float* Wp0 = &W[(size_t)(n0 + r0) * D_SZ + c0];
    const float* Wp1 = &W[(size_t)(n0 + r1) * D_SZ + c0];

    // prefetch tile 0
    float4 xa0 = *(const float4*)(Xp0);
    float4 xa1 = *(const float4*)(Xp1);
    float4 wa0 = *(const float4*)(Wp0);
    float4 wa1 = *(const float4*)(Wp1);

    for (int kk = 0; kk < D_SZ; kk += 32) {
        __syncthreads();   // previous tile fully consumed
        Xs[c0 + 0][r0] = xa0.x; Xs[c0 + 1][r0] = xa0.y;
        Xs[c0 + 2][r0] = xa0.z; Xs[c0 + 3][r0] = xa0.w;
        Xs[c0 + 0][r1] = xa1.x; Xs[c0 + 1][r1] = xa1.y;
        Xs[c0 + 2][r1] = xa1.z; Xs[c0 + 3][r1] = xa1.w;
        Ws[c0 + 0][r0] = wa0.x; Ws[c0 + 1][r0] = wa0.y;
        Ws[c0 + 2][r0] = wa0.z; Ws[c0 + 3][r0] = wa0.w;
        Ws[c0 + 0][r1] = wa1.x; Ws[c0 + 1][r1] = wa1.y;
        Ws[c0 + 2][r1] = wa1.z; Ws[c0 + 3][r1] = wa1.w;
        __syncthreads();

        // issue next tile's global loads now; compute below hides the latency
        if (kk + 32 < D_SZ) {
            xa0 = *(const float4*)(Xp0 + kk + 32);
            xa1 = *(const float4*)(Xp1 + kk + 32);
            wa0 = *(const float4*)(Wp0 + kk + 32);
            wa1 = *(const float4*)(Wp1 + kk + 32);
        }

#pragma unroll
        for (int k = 0; k < 32; ++k) {
            float4 a = *(const float4*)&Xs[k][ty * 4];
            float4 w = *(const float4*)&Ws[k][tx * 4];
            acc[0][0] = fmaf(a.x, w.x, acc[0][0]);
            acc[0][1] = fmaf(a.x, w.y, acc[0][1]);
            acc[0][2] = fmaf(a.x, w.z, acc[0][2]);
            acc[0][3] = fmaf(a.x, w.w, acc[0][3]);
            acc[1][0] = fmaf(a.y, w.x, acc[1][0]);
            acc[1][1] = fmaf(a.y, w.y, acc[1][1]);
            acc[1][2] = fmaf(a.y, w.z, acc[1][2]);
            acc[1][3] = fmaf(a.y, w.w, acc[1][3]);
            acc[2][0] = fmaf(a.z, w.x, acc[2][0]);
            acc[2][1] = fmaf(a.z, w.y, acc[2][1]);
            acc[2][2] = fmaf(a.z, w.z, acc[2][2]);
            acc[2][3] = fmaf(a.z, w.w, acc[2][3]);
            acc[3][0] = fmaf(a.w, w.x, acc[3][0]);
            acc[3][1] = fmaf(a.w, w.y, acc[3][1]);
            acc[3][2] = fmaf(a.w, w.z, acc[3][2]);
            acc[3][3] = fmaf(a.w, w.w, acc[3][3]);
        }
    }

    const float4 bv4 = *(const float4*)&bias[n0 + tx * 4];
#pragma unroll
    for (int r = 0; r < 4; ++r) {
        float4 o;
        o.x = acc[r][0] + bv4.x;
        o.y = acc[r][1] + bv4.y;
        o.z = acc[r][2] + bv4.z;
        o.w = acc[r][3] + bv4.w;
        *(float4*)&Y[(size_t)(m0 + ty * 4 + r) * D_SZ + n0 + tx * 4] = o;
    }
}

// ---------------------------------------------------------------------------
// Kernel 2: per batch row b: out[b,i] = sum_j exp(q_i*k_j - m_i)*v_j / den.
// m_i = q_i>=0 ? q_i*kmax : q_i*kmin (exact max of the rank-1 score row).
// log2 domain (k pre-scaled by log2 e): inner op = fma -> v_exp_f32 -> add
// -> fma per (i,j). One block (256 thr) per b; 2 rows/thread; (k,v) pairs
// staged interleaved in LDS, read as float4 = two j's per issue (broadcast,
// conflict-free). Separate accumulators per j-parity break the add chains.
// ---------------------------------------------------------------------------
__global__ __launch_bounds__(256) void attn_kernel(
    const float* __restrict__ qkv, float* __restrict__ out)
{
    const int b = blockIdx.x;
    const int t = threadIdx.x;

    const float* __restrict__ q = qkv + (size_t)b * D_SZ;
    const float* __restrict__ k = qkv + (size_t)B_SZ * D_SZ + (size_t)b * D_SZ;
    const float* __restrict__ v = qkv + (size_t)2 * B_SZ * D_SZ + (size_t)b * D_SZ;

    __shared__ float kv[D_SZ * 2];          // interleaved: k0,v0,k1,v1,...
    __shared__ float redmax[4], redmin[4];

    const float L = 1.44269504088896340736f;  // log2(e)

    // q loads issue early, overlap with staging
    const int i0 = t, i1 = t + 256;
    const float q0 = q[i0];
    const float q1 = q[i1];

    float kmaxL = -3.0e38f, kminL = 3.0e38f;
#pragma unroll
    for (int j = t; j < D_SZ; j += 256) {
        float kj = k[j] * L;
        float vj = v[j];
        *(float2*)&kv[2 * j] = make_float2(kj, vj);
        kmaxL = fmaxf(kmaxL, kj);
        kminL = fminf(kminL, kj);
    }
#pragma unroll
    for (int off = 32; off > 0; off >>= 1) {
        kmaxL = fmaxf(kmaxL, __shfl_xor(kmaxL, off));
        kminL = fminf(kminL, __shfl_xor(kminL, off));
    }
    const int wave = t >> 6;
    if ((t & 63) == 0) { redmax[wave] = kmaxL; redmin[wave] = kminL; }
    __syncthreads();   // also publishes kv[]
    kmaxL = fmaxf(fmaxf(redmax[0], redmax[1]), fmaxf(redmax[2], redmax[3]));
    kminL = fminf(fminf(redmin[0], redmin[1]), fminf(redmin[2], redmin[3]));

    const float c0 = (q0 >= 0.f) ? -(q0 * kmaxL) : -(q0 * kminL);
    const float c1 = (q1 >= 0.f) ? -(q1 * kmaxL) : -(q1 * kminL);

    float den0a = 0.f, den0b = 0.f, num0a = 0.f, num0b = 0.f;
    float den1a = 0.f, den1b = 0.f, num1a = 0.f, num1b = 0.f;
#pragma unroll 4
    for (int j = 0; j < D_SZ; j += 2) {
        float4 p = *(const float4*)&kv[2 * j];   // k_j, v_j, k_{j+1}, v_{j+1}
        float e0a = exp2_raw(fmaf(q0, p.x, c0));
        float e0b = exp2_raw(fmaf(q0, p.z, c0));
        float e1a = exp2_raw(fmaf(q1, p.x, c1));
        float e1b = exp2_raw(fmaf(q1, p.z, c1));
        den0a += e0a; den0b += e0b;
        den1a += e1a; den1b += e1b;
        num0a = fmaf(e0a, p.y, num0a);
        num0b = fmaf(e0b, p.w, num0b);
        num1a = fmaf(e1a, p.y, num1a);
        num1b = fmaf(e1b, p.w, num1b);
    }
    out[(size_t)b * D_SZ + i0] = (num0a + num0b) / (den0a + den0b);
    out[(size_t)b * D_SZ + i1] = (num1a + num1b) / (den1a + den1b);
}

extern "C" void kernel_launch(void* const* d_in, const int* in_sizes, int n_in,
                              void* d_out, int out_size, void* d_ws, size_t ws_size,
                              hipStream_t stream) {
    const float* query = (const float*)d_in[0];
    const float* key_  = (const float*)d_in[1];
    const float* value = (const float*)d_in[2];
    const float* Wq    = (const float*)d_in[3];
    const float* bq    = (const float*)d_in[4];
    const float* Wk    = (const float*)d_in[5];
    const float* bk    = (const float*)d_in[6];
    const float* Wv    = (const float*)d_in[7];
    const float* bv    = (const float*)d_in[8];
    float* out = (float*)d_out;

    float* qkv = (float*)d_ws;  // [3][B][D] fp32 = 12.6 MB

    dim3 g1(B_SZ / 64, D_SZ / 64, 3);
    qkv_gemm<<<g1, 256, 0, stream>>>(query, key_, value, Wq, bq, Wk, bk, Wv, bv, qkv);
    attn_kernel<<<B_SZ, 256, 0, stream>>>(qkv, out);
}

// Round 4
// 155.300 us; speedup vs baseline: 1.2634x; 1.2634x over previous
//
#include <hip/hip_runtime.h>
#include <hip/hip_bf16.h>

// Problem: B=2048, D=512, all fp32.
// q = query@Wq.T+bq ; k,v likewise. attn[b,i,j]=q_i*k_j (rank-1!),
// softmax over j, out[b,i] = sum_j softmax_j(q_i*k_j)*v_j.
//
// Round 4: projections via split-bf16 MFMA (C = Ahi*Bhi + Alo*Bhi + Ahi*Blo,
// fp32 accumulate; lo*lo term ~2^-14 rel, negligible). attn inner loop uses
// packed-fp32 (den,num across the two i-rows) hoping for v_pk_fma_f32.

#define B_SZ 2048
#define D_SZ 512

typedef __attribute__((ext_vector_type(2))) float  f32x2;
typedef __attribute__((ext_vector_type(4))) float  f32x4;
typedef __attribute__((ext_vector_type(8))) short  bf16x8;   // MFMA A/B carrier (guide §3)
typedef __attribute__((ext_vector_type(4))) unsigned short u16x4;

__device__ __forceinline__ float exp2_raw(float x) {
#if defined(__has_builtin) && __has_builtin(__builtin_amdgcn_exp2f)
    return __builtin_amdgcn_exp2f(x);
#else
    return exp2f(x);
#endif
}

// Truncation split: hi = top 16 bits of fp32; lo = bf16(trunc) of residual.
// |x - hi - lo| <= 2^-14 |x|  (residual <= 2^-7|x|, its trunc <= 2^-7 of that)
__device__ __forceinline__ void split1(float x, unsigned short& hi, unsigned short& lo) {
    unsigned int u = __float_as_uint(x);
    hi = (unsigned short)(u >> 16);
    float r = x - __uint_as_float(u & 0xFFFF0000u);
    lo = (unsigned short)(__float_as_uint(r) >> 16);
}

__device__ __forceinline__ void split4(const float4& x, u16x4& h, u16x4& l) {
    unsigned short hh, ll;
    split1(x.x, hh, ll); h.x = hh; l.x = ll;
    split1(x.y, hh, ll); h.y = hh; l.y = ll;
    split1(x.z, hh, ll); h.z = hh; l.z = ll;
    split1(x.w, hh, ll); h.w = hh; l.w = ll;
}

// ---------------------------------------------------------------------------
// Kernel 1: Y = X @ W^T + bias via split-bf16 MFMA. blockIdx.z selects q/k/v.
// 64x64 tile per block, 256 thr = 4 waves in 2x2; each wave: 2x2 frags of
// 16x16x32 MFMA, 3 terms chained into the same fp32 accumulator.
// LDS: hi/lo tiles [64][40] shorts (pad 40: frag b128 reads 2-way max = free).
// ---------------------------------------------------------------------------
__global__ __launch_bounds__(256) void qkv_gemm_mfma(
    const float* __restrict__ Xq, const float* __restrict__ Xk, const float* __restrict__ Xv,
    const float* __restrict__ Wq, const float* __restrict__ bq,
    const float* __restrict__ Wk, const float* __restrict__ bk,
    const float* __restrict__ Wv, const float* __restrict__ bv,
    float* __restrict__ qkv_out)
{
    const int which = blockIdx.z;
    const float* __restrict__ X    = (which == 0) ? Xq : (which == 1) ? Xk : Xv;
    const float* __restrict__ W    = (which == 0) ? Wq : (which == 1) ? Wk : Wv;
    const float* __restrict__ bias = (which == 0) ? bq : (which == 1) ? bk : bv;
    float* __restrict__ Y = qkv_out + (size_t)which * B_SZ * D_SZ;

    const int t    = threadIdx.x;
    const int lane = t & 63;
    const int wv   = t >> 6;          // wave id 0..3
    const int l15  = lane & 15;
    const int quad = lane >> 4;
    const int wm   = (wv >> 1) * 32;  // wave row offset in tile
    const int wn   = (wv & 1) * 32;   // wave col offset in tile
    const int m0   = blockIdx.x * 64;
    const int n0   = blockIdx.y * 64;

    __shared__ unsigned short Ahi[64][40], Alo[64][40];
    __shared__ unsigned short Bhi[64][40], Blo[64][40];

    f32x4 acc[2][2] = {{{0.f,0.f,0.f,0.f},{0.f,0.f,0.f,0.f}},
                       {{0.f,0.f,0.f,0.f},{0.f,0.f,0.f,0.f}}};

    // staging: 64 rows x 8 float4-cols per operand; 2 rows/thread
    const int r0 = t >> 3;            // 0..31
    const int c0 = (t & 7) * 4;       // 0,4,...,28
    const int r1 = r0 + 32;

    const float* Xp0 = &X[(size_t)(m0 + r0) * D_SZ + c0];
    const float* Xp1 = &X[(size_t)(m0 + r1) * D_SZ + c0];
    const float* Wp0 = &W[(size_t)(n0 + r0) * D_SZ + c0];
    const float* Wp1 = &W[(size_t)(n0 + r1) * D_SZ + c0];

    float4 xa0 = *(const float4*)(Xp0);
    float4 xa1 = *(const float4*)(Xp1);
    float4 wa0 = *(const float4*)(Wp0);
    float4 wa1 = *(const float4*)(Wp1);

    for (int kk = 0; kk < D_SZ; kk += 32) {
        __syncthreads();   // previous chunk's LDS fully consumed

        u16x4 h, l;
        split4(xa0, h, l); *(u16x4*)&Ahi[r0][c0] = h; *(u16x4*)&Alo[r0][c0] = l;
        split4(xa1, h, l); *(u16x4*)&Ahi[r1][c0] = h; *(u16x4*)&Alo[r1][c0] = l;
        split4(wa0, h, l); *(u16x4*)&Bhi[r0][c0] = h; *(u16x4*)&Blo[r0][c0] = l;
        split4(wa1, h, l); *(u16x4*)&Bhi[r1][c0] = h; *(u16x4*)&Blo[r1][c0] = l;

        __syncthreads();

        // prefetch next chunk's globals; MFMA section below hides the latency
        if (kk + 32 < D_SZ) {
            xa0 = *(const float4*)(Xp0 + kk + 32);
            xa1 = *(const float4*)(Xp1 + kk + 32);
            wa0 = *(const float4*)(Wp0 + kk + 32);
            wa1 = *(const float4*)(Wp1 + kk + 32);
        }

        // fragment loads: A[m=lane&15][k=quad*8+j] (m89/m120-verified layout)
        bf16x8 ah0 = *(const bf16x8*)&Ahi[wm + l15     ][quad * 8];
        bf16x8 ah1 = *(const bf16x8*)&Ahi[wm + 16 + l15][quad * 8];
        bf16x8 al0 = *(const bf16x8*)&Alo[wm + l15     ][quad * 8];
        bf16x8 al1 = *(const bf16x8*)&Alo[wm + 16 + l15][quad * 8];
        bf16x8 bh0 = *(const bf16x8*)&Bhi[wn + l15     ][quad * 8];
        bf16x8 bh1 = *(const bf16x8*)&Bhi[wn + 16 + l15][quad * 8];
        bf16x8 bl0 = *(const bf16x8*)&Blo[wn + l15     ][quad * 8];
        bf16x8 bl1 = *(const bf16x8*)&Blo[wn + 16 + l15][quad * 8];

        acc[0][0] = __builtin_amdgcn_mfma_f32_16x16x32_bf16(ah0, bh0, acc[0][0], 0, 0, 0);
        acc[0][0] = __builtin_amdgcn_mfma_f32_16x16x32_bf16(al0, bh0, acc[0][0], 0, 0, 0);
        acc[0][0] = __builtin_amdgcn_mfma_f32_16x16x32_bf16(ah0, bl0, acc[0][0], 0, 0, 0);
        acc[0][1] = __builtin_amdgcn_mfma_f32_16x16x32_bf16(ah0, bh1, acc[0][1], 0, 0, 0);
        acc[0][1] = __builtin_amdgcn_mfma_f32_16x16x32_bf16(al0, bh1, acc[0][1], 0, 0, 0);
        acc[0][1] = __builtin_amdgcn_mfma_f32_16x16x32_bf16(ah0, bl1, acc[0][1], 0, 0, 0);
        acc[1][0] = __builtin_amdgcn_mfma_f32_16x16x32_bf16(ah1, bh0, acc[1][0], 0, 0, 0);
        acc[1][0] = __builtin_amdgcn_mfma_f32_16x16x32_bf16(al1, bh0, acc[1][0], 0, 0, 0);
        acc[1][0] = __builtin_amdgcn_mfma_f32_16x16x32_bf16(ah1, bl0, acc[1][0], 0, 0, 0);
        acc[1][1] = __builtin_amdgcn_mfma_f32_16x16x32_bf16(ah1, bh1, acc[1][1], 0, 0, 0);
        acc[1][1] = __builtin_amdgcn_mfma_f32_16x16x32_bf16(al1, bh1, acc[1][1], 0, 0, 0);
        acc[1][1] = __builtin_amdgcn_mfma_f32_16x16x32_bf16(ah1, bl1, acc[1][1], 0, 0, 0);
    }

    // epilogue: C/D layout col=lane&15, row=quad*4+reg (m89/m91-verified)
#pragma unroll
    for (int ni = 0; ni < 2; ++ni) {
        const int col = n0 + wn + ni * 16 + l15;
        const float bb = bias[col];
#pragma unroll
        for (int mi = 0; mi < 2; ++mi) {
            const int row = m0 + wm + mi * 16 + quad * 4;
#pragma unroll
            for (int r = 0; r < 4; ++r) {
                Y[(size_t)(row + r) * D_SZ + col] = acc[mi][ni][r] + bb;
            }
        }
    }
}

// ---------------------------------------------------------------------------
// Kernel 2: out[b,i] = sum_j exp(q_i*k_j - m_i)*v_j / den, m_i via kmax/kmin
// (exact max of the rank-1 score row). log2 domain. One block per b, 256 thr,
// 2 rows/thread. Accumulators packed across the 2 rows as f32x2 so den/num
// updates can lower to v_pk_add_f32 / v_pk_fma_f32 (scalar fallback = old code).
// ---------------------------------------------------------------------------
__global__ __launch_bounds__(256) void attn_kernel(
    const float* __restrict__ qkv, float* __restrict__ out)
{
    const int b = blockIdx.x;
    const int t = threadIdx.x;

    const float* __restrict__ q = qkv + (size_t)b * D_SZ;
    const float* __restrict__ k = qkv + (size_t)B_SZ * D_SZ + (size_t)b * D_SZ;
    const float* __restrict__ v = qkv + (size_t)2 * B_SZ * D_SZ + (size_t)b * D_SZ;

    __shared__ float kv[D_SZ * 2];          // interleaved: k0,v0,k1,v1,...
    __shared__ float redmax[4], redmin[4];

    const float L = 1.44269504088896340736f;  // log2(e)

    const int i0 = t, i1 = t + 256;
    const float q0 = q[i0];
    const float q1 = q[i1];

    float kmaxL = -3.0e38f, kminL = 3.0e38f;
#pragma unroll
    for (int j = t; j < D_SZ; j += 256) {
        float kj = k[j] * L;
        float vj = v[j];
        *(float2*)&kv[2 * j] = make_float2(kj, vj);
        kmaxL = fmaxf(kmaxL, kj);
        kminL = fminf(kminL, kj);
    }
#pragma unroll
    for (int off = 32; off > 0; off >>= 1) {
        kmaxL = fmaxf(kmaxL, __shfl_xor(kmaxL, off));
        kminL = fminf(kminL, __shfl_xor(kminL, off));
    }
    const int wave = t >> 6;
    if ((t & 63) == 0) { redmax[wave] = kmaxL; redmin[wave] = kminL; }
    __syncthreads();   // also publishes kv[]
    kmaxL = fmaxf(fmaxf(redmax[0], redmax[1]), fmaxf(redmax[2], redmax[3]));
    kminL = fminf(fminf(redmin[0], redmin[1]), fminf(redmin[2], redmin[3]));

    const float c0 = (q0 >= 0.f) ? -(q0 * kmaxL) : -(q0 * kminL);
    const float c1 = (q1 >= 0.f) ? -(q1 * kmaxL) : -(q1 * kminL);

    // acc.x = row i0, acc.y = row i1; a/b copies break the dependency chains
    f32x2 den_a = {0.f, 0.f}, den_b = {0.f, 0.f};
    f32x2 num_a = {0.f, 0.f}, num_b = {0.f, 0.f};
#pragma unroll 8
    for (int j = 0; j < D_SZ; j += 2) {
        f32x4 p = *(const f32x4*)&kv[2 * j];   // k_j, v_j, k_{j+1}, v_{j+1}
        float e0a = exp2_raw(fmaf(q0, p.x, c0));
        float e1a = exp2_raw(fmaf(q1, p.x, c1));
        float e0b = exp2_raw(fmaf(q0, p.z, c0));
        float e1b = exp2_raw(fmaf(q1, p.z, c1));
        f32x2 ea = {e0a, e1a};
        f32x2 eb = {e0b, e1b};
        f32x2 va = {p.y, p.y};
        f32x2 vb = {p.w, p.w};
        den_a += ea;               // v_pk_add_f32
        den_b += eb;
        num_a += ea * va;          // v_pk_fma_f32
        num_b += eb * vb;
    }
    const f32x2 den = den_a + den_b;
    const f32x2 num = num_a + num_b;
    out[(size_t)b * D_SZ + i0] = num.x / den.x;
    out[(size_t)b * D_SZ + i1] = num.y / den.y;
}

extern "C" void kernel_launch(void* const* d_in, const int* in_sizes, int n_in,
                              void* d_out, int out_size, void* d_ws, size_t ws_size,
                              hipStream_t stream) {
    const float* query = (const float*)d_in[0];
    const float* key_  = (const float*)d_in[1];
    const float* value = (const float*)d_in[2];
    const float* Wq    = (const float*)d_in[3];
    const float* bq    = (const float*)d_in[4];
    const float* Wk    = (const float*)d_in[5];
    const float* bk    = (const float*)d_in[6];
    const float* Wv    = (const float*)d_in[7];
    const float* bv    = (const float*)d_in[8];
    float* out = (float*)d_out;

    float* qkv = (float*)d_ws;  // [3][B][D] fp32 = 12.6 MB

    dim3 g1(B_SZ / 64, D_SZ / 64, 3);
    qkv_gemm_mfma<<<g1, 256, 0, stream>>>(query, key_, value, Wq, bq, Wk, bk, Wv, bv, qkv);
    attn_kernel<<<B_SZ, 256, 0, stream>>>(qkv, out);
}